// Round 4
// baseline (347.440 us; speedup 1.0000x reference)
//
#include <hip/hip_runtime.h>
#include <hip/hip_cooperative_groups.h>
#include <hip/hip_bf16.h>
#include <math.h>

namespace cg = cooperative_groups;

#define C_   128
#define HW_  4096
#define OC_  100
#define NSTAT_ 32768.0f

typedef __bf16 bf16x8 __attribute__((ext_vector_type(8)));
typedef __bf16 bf16x4 __attribute__((ext_vector_type(4)));
typedef float  f32x4  __attribute__((ext_vector_type(4)));

// One cooperative kernel: grid 256 blocks x 512 threads, 2 grid syncs (the two BN stats).
// b = blk&7 everywhere -> batch b's x/t1c/t2c stay on XCD b's L2 for the whole kernel.
__global__ __launch_bounds__(512, 2) void k_fused(
    const float* __restrict__ x, const float* __restrict__ comp_w,
    const float* __restrict__ comp_g, const float* __restrict__ comp_b,
    const float* __restrict__ enc_w, const float* __restrict__ enc_g,
    const float* __restrict__ enc_b, float* __restrict__ out,
    float* __restrict__ t1c, float* __restrict__ t2c,
    float* __restrict__ cpS, float* __restrict__ cpQ,
    float* __restrict__ epS, float* __restrict__ epQ,
    __bf16* __restrict__ wprep)
{
    __shared__ __align__(16) char arena_[63360];   // max over phases (carafe: 240*132*2)
    __shared__ float lsc[64], lsh[64], esc[112], esh[112];

    cg::grid_group grid = cg::this_grid();
    const int blk = blockIdx.x;
    const int tid = threadIdx.x;
    const int b = blk & 7;
    const int wid = tid >> 6, lane = tid & 63;

    // ================= Phase A: 1x1 conv -> t1c channels-last + block-partial stats =========
    {
        const int chunk = blk >> 3;           // 32 chunks of 128 px per batch
        const int pxl = tid & 127, qtr = tid >> 7;
        const int px = chunk * 128 + pxl;
        const float* xb = x + (size_t)b * C_ * HW_ + px;
        const float* wb = comp_w + qtr * 16 * C_;

        float acc[16];
#pragma unroll
        for (int o = 0; o < 16; ++o) acc[o] = 0.f;
        for (int ic4 = 0; ic4 < 32; ++ic4) {
            float xv0 = xb[(ic4 * 4 + 0) * HW_];
            float xv1 = xb[(ic4 * 4 + 1) * HW_];
            float xv2 = xb[(ic4 * 4 + 2) * HW_];
            float xv3 = xb[(ic4 * 4 + 3) * HW_];
#pragma unroll
            for (int o = 0; o < 16; ++o) {
                const float4 wv = *(const float4*)(wb + o * C_ + ic4 * 4);
                acc[o] = fmaf(xv0, wv.x, acc[o]);
                acc[o] = fmaf(xv1, wv.y, acc[o]);
                acc[o] = fmaf(xv2, wv.z, acc[o]);
                acc[o] = fmaf(xv3, wv.w, acc[o]);
            }
        }
        float* tp = t1c + ((size_t)b * HW_ + px) * 64 + qtr * 16;
#pragma unroll
        for (int o4 = 0; o4 < 4; ++o4) {
            float4 st;
            st.x = acc[o4 * 4 + 0]; st.y = acc[o4 * 4 + 1];
            st.z = acc[o4 * 4 + 2]; st.w = acc[o4 * 4 + 3];
            *(float4*)(tp + o4 * 4) = st;
        }
        float* scrS = (float*)arena_;          // [8 waves][16]
        float* scrQ = scrS + 128;
#pragma unroll
        for (int o = 0; o < 16; ++o) {
            float s = acc[o], q = acc[o] * acc[o];
#pragma unroll
            for (int off = 32; off > 0; off >>= 1) {
                s += __shfl_down(s, off, 64);
                q += __shfl_down(q, off, 64);
            }
            if (lane == 0) { scrS[wid * 16 + o] = s; scrQ[wid * 16 + o] = q; }
        }
        // pack enc weights -> wprep[oc 112][k 576], k = tap*64+ic (63 blocks x 1024)
        if (blk < 63) {
#pragma unroll
            for (int u = 0; u < 2; ++u) {
                int idx = blk * 1024 + u * 512 + tid;
                int oc = idx / 576, k = idx - oc * 576;
                int tap = k >> 6, ic = k & 63;
                wprep[idx] = (oc < OC_) ? (__bf16)enc_w[((size_t)oc * 64 + ic) * 9 + tap]
                                        : (__bf16)0.f;
            }
        }
        __syncthreads();
        if (tid < 64) {
            int qr = tid >> 4, o = tid & 15;
            cpS[blk * 64 + tid] = scrS[(qr * 2) * 16 + o] + scrS[(qr * 2 + 1) * 16 + o];
            cpQ[blk * 64 + tid] = scrQ[(qr * 2) * 16 + o] + scrQ[(qr * 2 + 1) * 16 + o];
        }
    }
    __threadfence();
    grid.sync();

    // ================= Phase A2: reduce BN1 stats -> lsc/lsh (every block, redundant) =======
    {
        float* redS = (float*)arena_;          // [8][64]
        float* redQ = redS + 512;
        int ch = tid & 63, sl = tid >> 6;
        float S = 0.f, Q = 0.f;
        for (int j = 0; j < 32; ++j) {
            S += cpS[((sl * 32 + j) << 6) + ch];
            Q += cpQ[((sl * 32 + j) << 6) + ch];
        }
        redS[sl * 64 + ch] = S; redQ[sl * 64 + ch] = Q;
        __syncthreads();
        if (tid < 64) {
            float S2 = 0.f, Q2 = 0.f;
#pragma unroll
            for (int s = 0; s < 8; ++s) { S2 += redS[s * 64 + tid]; Q2 += redQ[s * 64 + tid]; }
            float invN = 1.0f / NSTAT_;
            float m = S2 * invN;
            float v = Q2 * invN - m * m;
            float rs = rsqrtf(v + 1e-5f);
            float sc = comp_g[tid] * rs;
            lsc[tid] = sc;
            lsh[tid] = comp_b[tid] - m * sc;
        }
        __syncthreads();
    }

    // ================= Phase B: 3x3 conv via MFMA bf16 -> t2c channels-last + partials ======
    {
        __bf16* xt = (__bf16*)arena_;                 // [10][18][72] bf16 = 25920 B
        float* esuml = (float*)(arena_ + 25920);      // 112
        float* esql = esuml + 112;
        const int tile = blk >> 3;
        const int ty0 = (tile >> 2) * 8, tx0 = (tile & 3) * 16;
        if (tid < 112) { esuml[tid] = 0.f; esql[tid] = 0.f; }
        __syncthreads();

        const float* tb = t1c + (size_t)b * HW_ * 64;
#pragma unroll
        for (int it = 0; it < 6; ++it) {
            int idx = it * 512 + tid;
            if (idx < 2880) {
                int pxi = idx >> 4, f4 = idx & 15;
                int yy = pxi / 18, xx = pxi - yy * 18;
                int gy = ty0 + yy - 1, gx = tx0 + xx - 1;
                float4 o = {0.f, 0.f, 0.f, 0.f};
                if (gy >= 0 && gy < 64 && gx >= 0 && gx < 64) {
                    float4 v = *(const float4*)(tb + ((size_t)(gy << 6) + gx) * 64 + f4 * 4);
                    float4 sc = *(const float4*)(lsc + f4 * 4);
                    float4 sh = *(const float4*)(lsh + f4 * 4);
                    float u;
                    u = fmaf(v.x, sc.x, sh.x); o.x = u / (1.f + __expf(-u));
                    u = fmaf(v.y, sc.y, sh.y); o.y = u / (1.f + __expf(-u));
                    u = fmaf(v.z, sc.z, sh.z); o.z = u / (1.f + __expf(-u));
                    u = fmaf(v.w, sc.w, sh.w); o.w = u / (1.f + __expf(-u));
                }
                bf16x4 st;
                st[0] = (__bf16)o.x; st[1] = (__bf16)o.y;
                st[2] = (__bf16)o.z; st[3] = (__bf16)o.w;
                *(bf16x4*)&xt[pxi * 72 + f4 * 4] = st;
            }
        }
        __syncthreads();

        int p = lane & 15, q = lane >> 4;
        f32x4 acc[7];
#pragma unroll
        for (int n = 0; n < 7; ++n) acc[n] = (f32x4){0.f, 0.f, 0.f, 0.f};

#pragma unroll
        for (int kk = 0; kk < 18; ++kk) {
            const int tap = kk >> 1, ich = (kk & 1) * 32;
            const int ky = tap / 3, kx = tap - ky * 3;
            bf16x8 a0 = *(const bf16x8*)&xt[((wid + ky) * 18 + p + kx) * 72 + ich + q * 8];
#pragma unroll
            for (int n = 0; n < 7; ++n) {
                bf16x8 bb = *(const bf16x8*)(wprep + ((size_t)(n * 16 + p)) * 576 + kk * 32 + q * 8);
                acc[n] = __builtin_amdgcn_mfma_f32_16x16x32_bf16(a0, bb, acc[n], 0, 0, 0);
            }
        }

        float* t2b = t2c + (size_t)b * HW_ * 112;
        int y = ty0 + wid;
#pragma unroll
        for (int n = 0; n < 7; ++n) {
            float s = 0.f, qq = 0.f;
            float* dst = t2b + ((size_t)y * 64 + tx0 + q * 4) * 112 + n * 16 + p;
#pragma unroll
            for (int rg = 0; rg < 4; ++rg) {
                float v = acc[n][rg];
                dst[(size_t)rg * 112] = v;
                s += v; qq += v * v;
            }
            s += __shfl_down(s, 32, 64);  s += __shfl_down(s, 16, 64);
            qq += __shfl_down(qq, 32, 64); qq += __shfl_down(qq, 16, 64);
            if (lane < 16) {
                atomicAdd(&esuml[n * 16 + lane], s);
                atomicAdd(&esql[n * 16 + lane], qq);
            }
        }
        __syncthreads();
        if (tid < 112) {
            epS[blk * 112 + tid] = esuml[tid];
            epQ[blk * 112 + tid] = esql[tid];
        }
    }
    __threadfence();
    grid.sync();

    // ================= Phase B2: reduce BN2 stats -> esc/esh =================
    {
        float* redS = (float*)arena_;          // [4][112]
        float* redQ = redS + 448;
        if (tid < 448) {
            int ch = tid % 112, sl = tid / 112;
            float S = 0.f, Q = 0.f;
            for (int j = 0; j < 64; ++j) {
                S += epS[(sl * 64 + j) * 112 + ch];
                Q += epQ[(sl * 64 + j) * 112 + ch];
            }
            redS[sl * 112 + ch] = S; redQ[sl * 112 + ch] = Q;
        }
        __syncthreads();
        if (tid < 112) {
            float S2 = redS[tid] + redS[112 + tid] + redS[224 + tid] + redS[336 + tid];
            float Q2 = redQ[tid] + redQ[112 + tid] + redQ[224 + tid] + redQ[336 + tid];
            float invN = 1.0f / NSTAT_;
            float m = S2 * invN;
            float v = Q2 * invN - m * m;
            float rs = rsqrtf(v + 1e-5f);
            float sc = (tid < OC_) ? enc_g[tid] * rs : 0.f;
            esc[tid] = sc;
            esh[tid] = (tid < OC_) ? enc_b[tid] - m * sc : 0.f;
        }
        __syncthreads();
    }

    // ================= Phase C: softmax + reassembly, 16x8 lowres tile (full-line writes) ====
    {
        __bf16* xt = (__bf16*)arena_;          // [12 rows][20 cols][128 ch pad 132]
        const int tile = blk >> 3;
        const int ly0 = (tile >> 2) * 8, lx0 = (tile & 3) * 16;

        const float* xb = x + (size_t)b * C_ * HW_;
#pragma unroll
        for (int it = 0; it < 15; ++it) {
            int idx = it * 512 + tid;          // 7680 = 240 px * 32 c4-groups
            int c4 = idx / 240;
            int r2 = idx - c4 * 240;
            int yy = r2 / 20, xx = r2 - yy * 20;
            int gy = ly0 - 2 + yy, gx = lx0 - 2 + xx;
            float v0 = 0.f, v1 = 0.f, v2 = 0.f, v3 = 0.f;
            if (gy >= 0 && gy < 64 && gx >= 0 && gx < 64) {
                size_t base = (size_t)(c4 * 4) * HW_ + (gy << 6) + gx;
                v0 = xb[base];
                v1 = xb[base + HW_];
                v2 = xb[base + 2 * HW_];
                v3 = xb[base + 3 * HW_];
            }
            bf16x4 st;
            st[0] = (__bf16)v0; st[1] = (__bf16)v1; st[2] = (__bf16)v2; st[3] = (__bf16)v3;
            *(bf16x4*)&xt[r2 * 132 + c4 * 4] = st;
        }
        __syncthreads();

        int lpx = tid & 127, cgp = tid >> 7;
        int ty = lpx >> 4, tx = lpx & 15;
        int iy = ly0 + ty, jx = lx0 + tx;

        float wgt[4][25];
        {
            const float* t2p = t2c + ((size_t)((b << 12) + (iy << 6) + jx)) * 112;
            float mx0 = -1e30f, mx1 = -1e30f, mx2 = -1e30f, mx3 = -1e30f;
#pragma unroll
            for (int k = 0; k < 25; ++k) {
                float4 lv = *(const float4*)(t2p + k * 4);
                float l0 = fmaf(lv.x, esc[4 * k + 0], esh[4 * k + 0]);
                float l1 = fmaf(lv.y, esc[4 * k + 1], esh[4 * k + 1]);
                float l2 = fmaf(lv.z, esc[4 * k + 2], esh[4 * k + 2]);
                float l3 = fmaf(lv.w, esc[4 * k + 3], esh[4 * k + 3]);
                wgt[0][k] = l0; wgt[1][k] = l1; wgt[2][k] = l2; wgt[3][k] = l3;
                mx0 = fmaxf(mx0, l0); mx1 = fmaxf(mx1, l1);
                mx2 = fmaxf(mx2, l2); mx3 = fmaxf(mx3, l3);
            }
            float mxs[4] = {mx0, mx1, mx2, mx3};
#pragma unroll
            for (int s = 0; s < 4; ++s) {
                float sum = 0.f;
#pragma unroll
                for (int k = 0; k < 25; ++k) {
                    float e = __expf(wgt[s][k] - mxs[s]);
                    wgt[s][k] = e;
                    sum += e;
                }
                float inv = 1.f / sum;
#pragma unroll
                for (int k = 0; k < 25; ++k) wgt[s][k] *= inv;
            }
        }

        float* ob = out + (size_t)b * C_ * 16384;
        int i0 = iy * 2, j0 = jx * 2;

#pragma unroll
        for (int c8 = 0; c8 < 4; ++c8) {
            int cbase = cgp * 32 + c8 * 8;
            float acc[4][8];
#pragma unroll
            for (int s = 0; s < 4; ++s)
#pragma unroll
                for (int e = 0; e < 8; ++e) acc[s][e] = 0.f;

#pragma unroll
            for (int dy = 0; dy < 5; ++dy)
#pragma unroll
                for (int dx = 0; dx < 5; ++dx) {
                    const __bf16* xp = &xt[((ty + dy) * 20 + tx + dx) * 132 + cbase];
                    bf16x4 lo = *(const bf16x4*)xp;
                    bf16x4 hi = *(const bf16x4*)(xp + 4);
                    float xf[8];
#pragma unroll
                    for (int e = 0; e < 4; ++e) { xf[e] = (float)lo[e]; xf[4 + e] = (float)hi[e]; }
#pragma unroll
                    for (int s = 0; s < 4; ++s) {
                        float wk = wgt[s][dy * 5 + dx];
#pragma unroll
                        for (int e = 0; e < 8; ++e) acc[s][e] = fmaf(wk, xf[e], acc[s][e]);
                    }
                }
#pragma unroll
            for (int e = 0; e < 8; ++e) {
                float2 r0; r0.x = acc[0][e]; r0.y = acc[1][e];
                float2 r1; r1.x = acc[2][e]; r1.y = acc[3][e];
                float* rb = ob + (size_t)(cbase + e) * 16384;
                *(float2*)(rb + i0 * 128 + j0) = r0;
                *(float2*)(rb + (i0 + 1) * 128 + j0) = r1;
            }
        }
    }
}

extern "C" void kernel_launch(void* const* d_in, const int* in_sizes, int n_in,
                              void* d_out, int out_size, void* d_ws, size_t ws_size,
                              hipStream_t stream) {
    const float* x      = (const float*)d_in[0];
    const float* comp_w = (const float*)d_in[1];
    const float* comp_g = (const float*)d_in[2];
    const float* comp_b = (const float*)d_in[3];
    const float* enc_w  = (const float*)d_in[4];
    const float* enc_g  = (const float*)d_in[5];
    const float* enc_b  = (const float*)d_in[6];
    float* out = (float*)d_out;

    float* ws = (float*)d_ws;
    float* t1c = ws;                       // 2,097,152 floats
    float* t2c = ws + 2097152;             // 3,670,016 floats
    float* cpS = ws + 5767168;             // 256*64
    float* cpQ = cpS + 16384;              // 256*64
    float* epS = cpQ + 16384;              // 256*112
    float* epQ = epS + 28672;              // 256*112
    __bf16* wprep = (__bf16*)(epQ + 28672);// 112*576 bf16

    void* args[] = { (void*)&x, (void*)&comp_w, (void*)&comp_g, (void*)&comp_b,
                     (void*)&enc_w, (void*)&enc_g, (void*)&enc_b, (void*)&out,
                     (void*)&t1c, (void*)&t2c, (void*)&cpS, (void*)&cpQ,
                     (void*)&epS, (void*)&epQ, (void*)&wprep };
    hipLaunchCooperativeKernel((const void*)k_fused, dim3(256), dim3(512), args, 0, stream);
}

// Round 5
// 206.502 us; speedup vs baseline: 1.6825x; 1.6825x over previous
//
#include <hip/hip_runtime.h>
#include <hip/hip_bf16.h>
#include <math.h>

#define C_   128
#define HW_  4096
#define OC_  100
#define NSTAT_ 32768.0f

typedef __bf16 bf16x8 __attribute__((ext_vector_type(8)));
typedef __bf16 bf16x4 __attribute__((ext_vector_type(4)));
typedef float  f32x4  __attribute__((ext_vector_type(4)));

// ---------------- K1: 1x1 conv -> t1c[b][px][64] bf16 + partial stats + wprep pack ---------
// grid 1024 = b(8) x chunk(32 of 128px) x half(4 of 16oc); 256 thr = 128 px x 2 octets.
__global__ __launch_bounds__(256, 4) void k_conv1(const float* __restrict__ x,
                                                  const float* __restrict__ w,
                                                  const float* __restrict__ wenc,
                                                  __bf16* __restrict__ t1c,
                                                  float* __restrict__ csum,
                                                  float* __restrict__ csq,
                                                  __bf16* __restrict__ wprep) {
    int blk = blockIdx.x;
    int b = blk & 7;
    int r = blk >> 3;                 // 0..127
    int chunk = r & 31;
    int half = r >> 5;                // 0..3
    int tid = threadIdx.x;
    int pxl = tid & 127, og = tid >> 7;
    int px = chunk * 128 + pxl;
    int ocb = half * 16 + og * 8;

    const float* xb = x + (size_t)b * C_ * HW_ + px;
    const float* wb = w + (size_t)ocb * C_;

    float acc[8];
#pragma unroll
    for (int o = 0; o < 8; ++o) acc[o] = 0.f;

    for (int ic4 = 0; ic4 < 32; ++ic4) {
        float xv0 = xb[(ic4 * 4 + 0) * HW_];
        float xv1 = xb[(ic4 * 4 + 1) * HW_];
        float xv2 = xb[(ic4 * 4 + 2) * HW_];
        float xv3 = xb[(ic4 * 4 + 3) * HW_];
#pragma unroll
        for (int o = 0; o < 8; ++o) {
            const float4 wv = *(const float4*)(wb + o * C_ + ic4 * 4);
            acc[o] = fmaf(xv0, wv.x, acc[o]);
            acc[o] = fmaf(xv1, wv.y, acc[o]);
            acc[o] = fmaf(xv2, wv.z, acc[o]);
            acc[o] = fmaf(xv3, wv.w, acc[o]);
        }
    }
    // bf16 store (16B per thread)
    {
        bf16x8 st;
#pragma unroll
        for (int o = 0; o < 8; ++o) st[o] = (__bf16)acc[o];
        *(bf16x8*)(t1c + ((size_t)b * HW_ + px) * 64 + ocb) = st;
    }
    // pack enc weights -> wprep[oc 112][k 576], k = tap*64+ic  (blocks 0..62, 1024 each)
    if (blk < 63) {
#pragma unroll
        for (int u = 0; u < 4; ++u) {
            int idx = blk * 1024 + u * 256 + tid;   // < 64512 = 112*576
            int oc = idx / 576, k = idx - oc * 576;
            int tap = k >> 6, ic = k & 63;
            wprep[idx] = (oc < OC_) ? (__bf16)wenc[((size_t)oc * 64 + ic) * 9 + tap]
                                    : (__bf16)0.f;
        }
    }
    // stats: shuffle-reduce fp32 accs
    __shared__ float sS[4][8], sQ[4][8];
    int wid = tid >> 6, lane = tid & 63;
#pragma unroll
    for (int o = 0; o < 8; ++o) {
        float s = acc[o], q = acc[o] * acc[o];
#pragma unroll
        for (int off = 32; off > 0; off >>= 1) {
            s += __shfl_down(s, off, 64);
            q += __shfl_down(q, off, 64);
        }
        if (lane == 0) { sS[wid][o] = s; sQ[wid][o] = q; }
    }
    __syncthreads();
    if (tid < 16) {
        int o = tid & 7, g = tid >> 3;   // g = octet (waves 2g, 2g+1)
        float S = sS[g * 2][o] + sS[g * 2 + 1][o];
        float Q = sQ[g * 2][o] + sQ[g * 2 + 1][o];
        atomicAdd(&csum[half * 16 + g * 8 + o], S);
        atomicAdd(&csq[half * 16 + g * 8 + o], Q);
    }
}

// ---------------- K2: 3x3 conv MFMA bf16, inline BN1 finalize, partial BN2 stats -----------
// grid 512 = b(8) x tile(64 of 8x8 px); 256 thr = 4 waves; wave = 2 y-rows (one 16px m-tile).
__global__ __launch_bounds__(256, 4) void k_conv3(const __bf16* __restrict__ t1c,
                                                  const __bf16* __restrict__ wprep,
                                                  const float* __restrict__ csum,
                                                  const float* __restrict__ csq,
                                                  const float* __restrict__ cg,
                                                  const float* __restrict__ cb,
                                                  float* __restrict__ t2c,
                                                  float* __restrict__ esum,
                                                  float* __restrict__ esq) {
    __shared__ __bf16 xt[10 * 10 * 72];      // [yy][xx][ic pad72] = 14400 B
    __shared__ float lsc[64], lsh[64];
    __shared__ float esuml[112], esql[112];

    int blk = blockIdx.x;
    int b = blk & 7;
    int tile = blk >> 3;
    int ty0 = (tile >> 3) * 8, tx0 = (tile & 7) * 8;
    int tid = threadIdx.x;
    if (tid < 112) { esuml[tid] = 0.f; esql[tid] = 0.f; }
    if (tid >= 128 && tid < 192) {
        int c = tid - 128;
        float invN = 1.0f / NSTAT_;
        float m = csum[c] * invN;
        float v = csq[c] * invN - m * m;
        float rs = rsqrtf(v + 1e-5f);
        float sc = cg[c] * rs;
        lsc[c] = sc;
        lsh[c] = cb[c] - m * sc;
    }
    __syncthreads();

    // stage BN+SiLU(t1) 10x10 halo -> LDS bf16 (1600 jobs of 4 ic)
    const __bf16* tb = t1c + (size_t)b * HW_ * 64;
#pragma unroll
    for (int it = 0; it < 7; ++it) {
        int idx = it * 256 + tid;
        if (idx < 1600) {
            int pxi = idx >> 4, f4 = idx & 15;
            int yy = pxi / 10, xx = pxi - yy * 10;
            int gy = ty0 + yy - 1, gx = tx0 + xx - 1;
            float o0 = 0.f, o1 = 0.f, o2 = 0.f, o3 = 0.f;
            if (gy >= 0 && gy < 64 && gx >= 0 && gx < 64) {
                bf16x4 v = *(const bf16x4*)(tb + ((size_t)(gy << 6) + gx) * 64 + f4 * 4);
                float4 sc = *(const float4*)(lsc + f4 * 4);
                float4 sh = *(const float4*)(lsh + f4 * 4);
                float u;
                u = fmaf((float)v[0], sc.x, sh.x); o0 = u / (1.f + __expf(-u));
                u = fmaf((float)v[1], sc.y, sh.y); o1 = u / (1.f + __expf(-u));
                u = fmaf((float)v[2], sc.z, sh.z); o2 = u / (1.f + __expf(-u));
                u = fmaf((float)v[3], sc.w, sh.w); o3 = u / (1.f + __expf(-u));
            }
            bf16x4 st;
            st[0] = (__bf16)o0; st[1] = (__bf16)o1; st[2] = (__bf16)o2; st[3] = (__bf16)o3;
            *(bf16x4*)&xt[pxi * 72 + f4 * 4] = st;
        }
    }
    __syncthreads();

    int lane = tid & 63, wv = tid >> 6;      // wave owns y rows {2wv, 2wv+1}
    int p = lane & 15, q = lane >> 4;
    int ya = 2 * wv + (p >> 3), xa = p & 7;  // A-frag pixel for lane

    f32x4 acc[7];
#pragma unroll
    for (int n = 0; n < 7; ++n) acc[n] = (f32x4){0.f, 0.f, 0.f, 0.f};

#pragma unroll
    for (int kk = 0; kk < 18; ++kk) {
        const int tap = kk >> 1, ich = (kk & 1) * 32;
        const int ky = tap / 3, kx = tap - ky * 3;
        bf16x8 a0 = *(const bf16x8*)&xt[((ya + ky) * 10 + xa + kx) * 72 + ich + q * 8];
#pragma unroll
        for (int n = 0; n < 7; ++n) {
            bf16x8 bb = *(const bf16x8*)(wprep + ((size_t)(n * 16 + p)) * 576 + kk * 32 + q * 8);
            acc[n] = __builtin_amdgcn_mfma_f32_16x16x32_bf16(a0, bb, acc[n], 0, 0, 0);
        }
    }

    // D: col(oc)=lane&15, row m' = q*4+rg -> y=2wv+(m'>>3), x=m'&7
    float* t2b = t2c + (size_t)b * HW_ * 112;
#pragma unroll
    for (int n = 0; n < 7; ++n) {
        float s = 0.f, qq = 0.f;
#pragma unroll
        for (int rg = 0; rg < 4; ++rg) {
            int mp = q * 4 + rg;
            int y = ty0 + 2 * wv + (mp >> 3), xo = tx0 + (mp & 7);
            float v = acc[n][rg];
            t2b[((size_t)y * 64 + xo) * 112 + n * 16 + p] = v;
            s += v; qq += v * v;
        }
        s += __shfl_down(s, 32, 64);  s += __shfl_down(s, 16, 64);
        qq += __shfl_down(qq, 32, 64); qq += __shfl_down(qq, 16, 64);
        if (lane < 16) {
            atomicAdd(&esuml[n * 16 + lane], s);
            atomicAdd(&esql[n * 16 + lane], qq);
        }
    }
    __syncthreads();
    if (tid < 112) {
        atomicAdd(&esum[tid], esuml[tid]);
        atomicAdd(&esq[tid], esql[tid]);
    }
}

// ---------------- K3: inline BN2 + softmax + reassembly ----------------
// grid 512 = b(8) x tile(64: 16w x 4t lowres = 32x8 hires); 256 thr = 1 hires px each.
// Full 128B output lines; x halo staged fp32 in 4 channel-stages of 32.
__global__ __launch_bounds__(256, 4) void k_carafe(const float* __restrict__ x,
                                                   const float* __restrict__ t2c,
                                                   const float* __restrict__ esum,
                                                   const float* __restrict__ esq,
                                                   const float* __restrict__ eg,
                                                   const float* __restrict__ eb,
                                                   float* __restrict__ out) {
    __shared__ float xt[160 * 36];           // [halo px 8x20][ch 32 pad 36] = 23040 B
    __shared__ float esc[112], esh[112];

    int blk = blockIdx.x;
    int b = blk & 7;
    int tile = blk >> 3;
    int ly0 = (tile >> 2) * 4, lx0 = (tile & 3) * 16;
    int tid = threadIdx.x;
    if (tid < 112) {
        float invN = 1.0f / NSTAT_;
        float m = esum[tid] * invN;
        float v = esq[tid] * invN - m * m;
        float rs = rsqrtf(v + 1e-5f);
        float sc = (tid < OC_) ? eg[tid] * rs : 0.f;
        esc[tid] = sc;
        esh[tid] = (tid < OC_) ? eb[tid] - m * sc : 0.f;
    }
    __syncthreads();

    int row = tid >> 5, col = tid & 31;      // hires offsets in 32x8 tile
    int iy = ly0 + (row >> 1), jx = lx0 + (col >> 1);
    int s = (row & 1) * 2 + (col & 1);
    int ty = row >> 1, tx = col >> 1;        // lowres offsets

    // softmax over this subpixel's 25 taps
    float wgt[25];
    {
        const float* t2p = t2c + ((size_t)((b << 12) + (iy << 6) + jx)) * 112 + s;
        float mx = -1e30f;
#pragma unroll
        for (int k = 0; k < 25; ++k) {
            float l = fmaf(t2p[k * 4], esc[4 * k + s], esh[4 * k + s]);
            wgt[k] = l;
            mx = fmaxf(mx, l);
        }
        float sum = 0.f;
#pragma unroll
        for (int k = 0; k < 25; ++k) {
            float e = __expf(wgt[k] - mx);
            wgt[k] = e;
            sum += e;
        }
        float inv = 1.f / sum;
#pragma unroll
        for (int k = 0; k < 25; ++k) wgt[k] *= inv;
    }

    const float* xb = x + (size_t)b * C_ * HW_;
    float* op = out + (size_t)b * C_ * 16384 + (size_t)(ly0 * 2 + row) * 128 + lx0 * 2 + col;

    for (int cq = 0; cq < 4; ++cq) {
        __syncthreads();
        // stage 160 halo px x 32 ch fp32 (1280 jobs of 4 ch)
#pragma unroll
        for (int it = 0; it < 5; ++it) {
            int idx = it * 256 + tid;        // < 1280
            int c4 = idx / 160;
            int r2 = idx - c4 * 160;
            int yy = r2 / 20, xx = r2 - yy * 20;
            int gy = ly0 - 2 + yy, gx = lx0 - 2 + xx;
            float v0 = 0.f, v1 = 0.f, v2 = 0.f, v3 = 0.f;
            if (gy >= 0 && gy < 64 && gx >= 0 && gx < 64) {
                size_t base = (size_t)(cq * 32 + c4 * 4) * HW_ + (gy << 6) + gx;
                v0 = xb[base];
                v1 = xb[base + HW_];
                v2 = xb[base + 2 * HW_];
                v3 = xb[base + 3 * HW_];
            }
            float* d = &xt[r2 * 36 + c4 * 4];
            d[0] = v0; d[1] = v1; d[2] = v2; d[3] = v3;
        }
        __syncthreads();

        float acc[32];
#pragma unroll
        for (int e = 0; e < 32; ++e) acc[e] = 0.f;
#pragma unroll
        for (int dy = 0; dy < 5; ++dy)
#pragma unroll
            for (int dx = 0; dx < 5; ++dx) {
                const float* xp = &xt[((ty + dy) * 20 + tx + dx) * 36];
                float wk = wgt[dy * 5 + dx];
#pragma unroll
                for (int c4 = 0; c4 < 8; ++c4) {
                    f32x4 xv = *(const f32x4*)(xp + c4 * 4);
                    acc[c4 * 4 + 0] = fmaf(wk, xv[0], acc[c4 * 4 + 0]);
                    acc[c4 * 4 + 1] = fmaf(wk, xv[1], acc[c4 * 4 + 1]);
                    acc[c4 * 4 + 2] = fmaf(wk, xv[2], acc[c4 * 4 + 2]);
                    acc[c4 * 4 + 3] = fmaf(wk, xv[3], acc[c4 * 4 + 3]);
                }
            }
#pragma unroll
        for (int e = 0; e < 32; ++e)
            op[(size_t)(cq * 32 + e) * 16384] = acc[e];
    }
}

extern "C" void kernel_launch(void* const* d_in, const int* in_sizes, int n_in,
                              void* d_out, int out_size, void* d_ws, size_t ws_size,
                              hipStream_t stream) {
    const float* x      = (const float*)d_in[0];
    const float* comp_w = (const float*)d_in[1];
    const float* comp_g = (const float*)d_in[2];
    const float* comp_b = (const float*)d_in[3];
    const float* enc_w  = (const float*)d_in[4];
    const float* enc_g  = (const float*)d_in[5];
    const float* enc_b  = (const float*)d_in[6];
    float* out = (float*)d_out;

    float* ws = (float*)d_ws;
    __bf16* t1c = (__bf16*)ws;             // 8*4096*64 bf16 = 4 MB
    float* t2c  = ws + 1048576;            // 8*4096*112 fp32 = 14.7 MB
    float* st   = ws + 1048576 + 3670016;
    float* csum = st;                      // 64
    float* csq  = st + 64;                 // 64
    float* esum = st + 128;                // 112
    float* esq  = st + 240;                // 112
    __bf16* wprep = (__bf16*)(st + 352);   // 112*576 bf16

    hipMemsetAsync(st, 0, 352 * sizeof(float), stream);
    k_conv1<<<1024, 256, 0, stream>>>(x, comp_w, enc_w, t1c, csum, csq, wprep);
    k_conv3<<<512, 256, 0, stream>>>(t1c, wprep, csum, csq, comp_g, comp_b, t2c, esum, esq);
    k_carafe<<<512, 256, 0, stream>>>(x, t2c, esum, esq, enc_g, enc_b, out);
}